// Round 10
// baseline (77.748 us; speedup 1.0000x reference)
//
#include <hip/hip_runtime.h>
#include <hip/hip_bf16.h>

typedef float f32x4 __attribute__((ext_vector_type(4)));
typedef float f32x16 __attribute__((ext_vector_type(16)));
typedef __bf16 bf16x8 __attribute__((ext_vector_type(8)));
typedef int v2i __attribute__((ext_vector_type(2)));
typedef unsigned short ushort_t;

#define SEQ 2048
#define BATCH 2
#define EMS 256
#define NHEAD 8
#define HEAD 32
#define BH (BATCH*NHEAD)
#define LOG2E 1.4426950408889634f
#define QSCALE 0.2550348211f      /* log2(e)/sqrt(32) */
#define THRS 11.5415603f          /* 8*log2(e): defer-max bound e^8 */

static __device__ __forceinline__ ushort_t f2bfbits(float f) {
    unsigned int u = __float_as_uint(f);
    u += 0x7fffu + ((u >> 16) & 1u);
    return (ushort_t)(u >> 16);
}

static __device__ __forceinline__ unsigned cvtpk(float lo, float hi) {
    unsigned r;
    asm("v_cvt_pk_bf16_f32 %0, %1, %2" : "=v"(r) : "v"(lo), "v"(hi));
    return r;
}

static __device__ __forceinline__ float exp2a(float x) {
    float r;
    asm("v_exp_f32 %0, %1" : "=v"(r) : "v"(x));
    return r;
}

static __device__ __forceinline__ bf16x8 cvt8(const float* p) {
    float4 a = *reinterpret_cast<const float4*>(p);
    float4 b = *reinterpret_cast<const float4*>(p + 4);
    union { bf16x8 v; uint4 u; } x;
    x.u.x = cvtpk(a.x, a.y);
    x.u.y = cvtpk(a.z, a.w);
    x.u.z = cvtpk(b.x, b.y);
    x.u.w = cvtpk(b.z, b.w);
    return x.v;
}

// ---------------- QKV projection: wave = 32 rows x 64 cols of [Q|K|V] ------
__global__ __launch_bounds__(256) void qkv_proj(
    const float* __restrict__ em,
    const float* __restrict__ Wq, const float* __restrict__ bq,
    const float* __restrict__ Wk, const float* __restrict__ bk,
    const float* __restrict__ Wv, const float* __restrict__ bv,
    ushort_t* __restrict__ Qb, ushort_t* __restrict__ Kb,
    ushort_t* __restrict__ Vb)
{
    int wid = blockIdx.x * 4 + (threadIdx.x >> 6);   // < 1536
    int l   = threadIdx.x & 63;
    int l15 = l & 15, lq = l >> 4;
    int rb = wid / 12, cg = wid % 12;
    int r0 = rb * 32, c0 = cg * 64;
    int sel = c0 >> 8;                       // 0=Q 1=K 2=V (uniform per wave)
    const float* W    = sel == 0 ? Wq : (sel == 1 ? Wk : Wv);
    const float* bias = sel == 0 ? bq : (sel == 1 ? bk : bv);
    ushort_t*    dst  = sel == 0 ? Qb : (sel == 1 ? Kb : Vb);
    int cb = c0 & 255;

    f32x4 acc[2][4];
    #pragma unroll
    for (int m = 0; m < 2; m++)
        #pragma unroll
        for (int n = 0; n < 4; n++) acc[m][n] = (f32x4){0.f, 0.f, 0.f, 0.f};

    #pragma unroll
    for (int kk = 0; kk < 8; kk++) {
        int k0 = kk * 32;
        bf16x8 af[2], bfm[4];
        #pragma unroll
        for (int m = 0; m < 2; m++)
            af[m] = cvt8(em + (size_t)(r0 + m * 16 + l15) * EMS + k0 + lq * 8);
        #pragma unroll
        for (int n = 0; n < 4; n++)
            bfm[n] = cvt8(W + (size_t)(cb + n * 16 + l15) * EMS + k0 + lq * 8);
        #pragma unroll
        for (int m = 0; m < 2; m++)
            #pragma unroll
            for (int n = 0; n < 4; n++)
                acc[m][n] = __builtin_amdgcn_mfma_f32_16x16x32_bf16(af[m], bfm[n], acc[m][n], 0, 0, 0);
    }

    float scale = (sel == 0) ? QSCALE : 1.0f;   // log2e/sqrt(D) folded into Q
    #pragma unroll
    for (int m = 0; m < 2; m++) {
        #pragma unroll
        for (int n = 0; n < 4; n++) {
            int c = cb + n * 16 + l15;
            float bv_ = bias[c];
            int h = c >> 5, d = c & 31;
            #pragma unroll
            for (int r = 0; r < 4; r++) {
                int row = r0 + m * 16 + lq * 4 + r;   // C/D: row=(l>>4)*4+reg, col=l&15
                int s = row >> 1, b = row & 1;
                ushort_t v = f2bfbits((acc[m][n][r] + bv_) * scale);
                dst[((size_t)(b * NHEAD + h) * SEQ + s) * HEAD + d] = v;
            }
        }
    }
}

// ---------------- V transpose: [bh][s][d] -> blocked Vt2[bh][kblk][32d][32s]
__global__ __launch_bounds__(256) void vtrans(const ushort_t* __restrict__ Vb,
                                              ushort_t* __restrict__ Vt2)
{
    __shared__ ushort_t t[64][40];      // 80B row stride: 16B-aligned uint4 slots
    int g = blockIdx.x;
    int bh = g & 15, st = g >> 4;       // 32 tiles of 64 s
    int s0 = st * 64;
    int tid = threadIdx.x;

    {
        int sl = tid >> 2, d0 = (tid & 3) * 8;
        uint4 v = *(const uint4*)(Vb + ((size_t)bh * SEQ + s0 + sl) * HEAD + d0);
        *(uint4*)&t[sl][d0] = v;
    }
    __syncthreads();
    {
        int kb_l = tid >> 7, rem = tid & 127;
        int d = rem >> 2, si0 = (rem & 3) * 8;
        union { ushort_t u[8]; uint4 q; } o;
        #pragma unroll
        for (int j = 0; j < 8; j++) o.u[j] = t[kb_l * 32 + si0 + j][d];
        *(uint4*)(Vt2 + (((size_t)bh * 64 + (s0 >> 5) + kb_l) * 32 + d) * 32 + si0) = o.q;
    }
}

// ---------------- Flash attention: 32x32 MFMA, mask fused in the pipeline --
// Block = (b,h,32q);  h = blockIdx>>7 so the 8 heads sharing a (b,qt) mask
// stripe have IDs == rem (mod 8) -> same XCD -> mask row fetched from HBM
// once, served 8x from that XCD's L2.  Mask tile (4x float4/lane) prefetched
// one tile ahead alongside K/V; no flags, no separate scan pass.
__global__ __launch_bounds__(256, 4) void attn(
    const ushort_t* __restrict__ Qb, const ushort_t* __restrict__ Kb,
    const ushort_t* __restrict__ Vt2, const float* __restrict__ mask,
    float* __restrict__ out)
{
    int g   = blockIdx.x;
    int h   = g >> 7;             // 0..7
    int rem = g & 127;
    int b   = rem >> 6;           // 0..1
    int qt  = rem & 63;           // 0..63
    int bh = b * NHEAD + h;
    int w  = threadIdx.x >> 6;
    int l  = threadIdx.x & 63;
    int l31 = l & 31, hi = l >> 5;
    int qs0 = qt * 32;

    __shared__ float oacc[4][32][36];
    __shared__ float om[4][32], ol[4][32];

    const ushort_t* qrow = Qb + ((size_t)bh * SEQ + qs0 + l31) * HEAD + hi * 8;
    bf16x8 qf0 = *(const bf16x8*)(qrow);        // d 0..15 fragment
    bf16x8 qf1 = *(const bf16x8*)(qrow + 16);   // d 16..31

    f32x16 acc = {};
    float mrun = -1e30f, lsum = 0.f;            // per-lane, q = l31

    int k0 = w * (SEQ / 4);
    const ushort_t* kbase = Kb  + ((size_t)bh * SEQ + k0 + l31) * HEAD + hi * 8;
    const ushort_t* vbase = Vt2 + ((size_t)bh * 64 + (k0 >> 5)) * 1024 + l31 * 32 + hi * 8;
    const float*    mbase = mask + (size_t)b * SEQ * SEQ
                          + (size_t)(qs0 + l31) * SEQ + k0 + hi * 4;

    // prefetch tile 0
    bf16x8 kc0 = *(const bf16x8*)(kbase);
    bf16x8 kc1 = *(const bf16x8*)(kbase + 16);
    bf16x8 vc0 = *(const bf16x8*)(vbase);
    bf16x8 vc1 = *(const bf16x8*)(vbase + 16);
    float4 mc0 = *(const float4*)(mbase);
    float4 mc1 = *(const float4*)(mbase + 8);
    float4 mc2 = *(const float4*)(mbase + 16);
    float4 mc3 = *(const float4*)(mbase + 24);

    const int NT = (SEQ / 4) / 32;   // 16 tiles per wave
    for (int kt = 0; kt < NT; kt++) {
        int ktn = (kt + 1 < NT) ? kt + 1 : 0;   // wrap: prefetch discarded
        f32x16 st = {};
        st = __builtin_amdgcn_mfma_f32_32x32x16_bf16(kc0, qf0, st, 0, 0, 0);
        st = __builtin_amdgcn_mfma_f32_32x32x16_bf16(kc1, qf1, st, 0, 0, 0);

        // prefetch next tile (overlaps softmax + PV)
        bf16x8 kn0 = *(const bf16x8*)(kbase + ktn * 1024);
        bf16x8 kn1 = *(const bf16x8*)(kbase + ktn * 1024 + 16);
        bf16x8 vn0 = *(const bf16x8*)(vbase + ktn * 1024);
        bf16x8 vn1 = *(const bf16x8*)(vbase + ktn * 1024 + 16);
        const float* mrn = mbase + ktn * 32;
        float4 mn0 = *(const float4*)(mrn);
        float4 mn1 = *(const float4*)(mrn + 8);
        float4 mn2 = *(const float4*)(mrn + 16);
        float4 mn3 = *(const float4*)(mrn + 24);

        // add mask (nat-log) into log2-space scores: st[j], k=(j&3)+8*(j>>2)+4*hi
        st[0]  = fmaf(mc0.x, LOG2E, st[0]);  st[1]  = fmaf(mc0.y, LOG2E, st[1]);
        st[2]  = fmaf(mc0.z, LOG2E, st[2]);  st[3]  = fmaf(mc0.w, LOG2E, st[3]);
        st[4]  = fmaf(mc1.x, LOG2E, st[4]);  st[5]  = fmaf(mc1.y, LOG2E, st[5]);
        st[6]  = fmaf(mc1.z, LOG2E, st[6]);  st[7]  = fmaf(mc1.w, LOG2E, st[7]);
        st[8]  = fmaf(mc2.x, LOG2E, st[8]);  st[9]  = fmaf(mc2.y, LOG2E, st[9]);
        st[10] = fmaf(mc2.z, LOG2E, st[10]); st[11] = fmaf(mc2.w, LOG2E, st[11]);
        st[12] = fmaf(mc3.x, LOG2E, st[12]); st[13] = fmaf(mc3.y, LOG2E, st[13]);
        st[14] = fmaf(mc3.z, LOG2E, st[14]); st[15] = fmaf(mc3.w, LOG2E, st[15]);

        float x0 = fmaxf(st[0], st[1]),  x1 = fmaxf(st[2], st[3]);
        float x2 = fmaxf(st[4], st[5]),  x3 = fmaxf(st[6], st[7]);
        float x4 = fmaxf(st[8], st[9]),  x5 = fmaxf(st[10], st[11]);
        float x6 = fmaxf(st[12], st[13]), x7 = fmaxf(st[14], st[15]);
        float lmax = fmaxf(fmaxf(fmaxf(x0, x1), fmaxf(x2, x3)),
                           fmaxf(fmaxf(x4, x5), fmaxf(x6, x7)));

        if (__any(lmax > mrun + THRS)) {   // defer-max rescale (rare)
            v2i sw = __builtin_amdgcn_permlane32_swap(
                __float_as_int(lmax), __float_as_int(lmax), false, false);
            float pm = fmaxf(fmaxf(lmax, __int_as_float(sw.x)), __int_as_float(sw.y));
            float nm = fmaxf(mrun, pm);
            float sc = exp2a(mrun - nm);
            lsum *= sc;
            #pragma unroll
            for (int j = 0; j < 16; j++) acc[j] *= sc;   // q = own lane: no shuffle
            mrun = nm;
        }

        float ev[16];
        #pragma unroll
        for (int j = 0; j < 16; j++) ev[j] = exp2a(st[j] - mrun);
        lsum += (((ev[0]+ev[1])+(ev[2]+ev[3])) + ((ev[4]+ev[5])+(ev[6]+ev[7])))
              + (((ev[8]+ev[9])+(ev[10]+ev[11])) + ((ev[12]+ev[13])+(ev[14]+ev[15])));

        unsigned pk[8];
        #pragma unroll
        for (int j = 0; j < 8; j++) pk[j] = cvtpk(ev[2 * j], ev[2 * j + 1]);
        // P^T B-operand repack via permlane32_swap (HW-verified R7):
        v2i p0 = __builtin_amdgcn_permlane32_swap((int)pk[0], (int)pk[2], false, false);
        v2i p1 = __builtin_amdgcn_permlane32_swap((int)pk[1], (int)pk[3], false, false);
        v2i p2 = __builtin_amdgcn_permlane32_swap((int)pk[4], (int)pk[6], false, false);
        v2i p3 = __builtin_amdgcn_permlane32_swap((int)pk[5], (int)pk[7], false, false);
        union { int i[4]; bf16x8 v; } pf0, pf1;
        pf0.i[0] = p0.x; pf0.i[1] = p1.x; pf0.i[2] = p0.y; pf0.i[3] = p1.y;
        pf1.i[0] = p2.x; pf1.i[1] = p3.x; pf1.i[2] = p2.y; pf1.i[3] = p3.y;

        acc = __builtin_amdgcn_mfma_f32_32x32x16_bf16(vc0, pf0.v, acc, 0, 0, 0);
        acc = __builtin_amdgcn_mfma_f32_32x32x16_bf16(vc1, pf1.v, acc, 0, 0, 0);

        kc0 = kn0; kc1 = kn1; vc0 = vn0; vc1 = vn1;
        mc0 = mn0; mc1 = mn1; mc2 = mn2; mc3 = mn3;
    }

    // lsum across the two half-lanes of each q
    v2i sl = __builtin_amdgcn_permlane32_swap(
        __float_as_int(lsum), __float_as_int(lsum), false, false);
    float lt = __int_as_float(sl.x) + __int_as_float(sl.y);
    if (hi == 0) { om[w][l31] = mrun; ol[w][l31] = lt; }

    #pragma unroll
    for (int gg = 0; gg < 4; gg++) {    // acc reg 4g+j -> d = j + 8g + 4hi
        f32x4 vv = { acc[4*gg], acc[4*gg+1], acc[4*gg+2], acc[4*gg+3] };
        *(f32x4*)&oacc[w][l31][8 * gg + 4 * hi] = vv;
    }
    __syncthreads();

    // merge 4 k-quarters: 1024 outputs, one float4 per thread
    int t = threadIdx.x;
    int q = t >> 3, d4 = (t & 7) * 4;
    float m0 = om[0][q], m1 = om[1][q], m2 = om[2][q], m3 = om[3][q];
    float mg = fmaxf(fmaxf(m0, m1), fmaxf(m2, m3));
    float w0_ = exp2a(m0 - mg), w1_ = exp2a(m1 - mg);
    float w2_ = exp2a(m2 - mg), w3_ = exp2a(m3 - mg);
    float lg = w0_ * ol[0][q] + w1_ * ol[1][q] + w2_ * ol[2][q] + w3_ * ol[3][q];
    float inv = 1.0f / lg;
    float4 o;
    o.x = (w0_*oacc[0][q][d4]   + w1_*oacc[1][q][d4]   + w2_*oacc[2][q][d4]   + w3_*oacc[3][q][d4])   * inv;
    o.y = (w0_*oacc[0][q][d4+1] + w1_*oacc[1][q][d4+1] + w2_*oacc[2][q][d4+1] + w3_*oacc[3][q][d4+1]) * inv;
    o.z = (w0_*oacc[0][q][d4+2] + w1_*oacc[1][q][d4+2] + w2_*oacc[2][q][d4+2] + w3_*oacc[3][q][d4+2]) * inv;
    o.w = (w0_*oacc[0][q][d4+3] + w1_*oacc[1][q][d4+3] + w2_*oacc[2][q][d4+3] + w3_*oacc[3][q][d4+3]) * inv;
    *(float4*)(out + ((size_t)(qs0 + q) * BATCH + b) * EMS + h * HEAD + d4) = o;
}

extern "C" void kernel_launch(void* const* d_in, const int* in_sizes, int n_in,
                              void* d_out, int out_size, void* d_ws, size_t ws_size,
                              hipStream_t stream) {
    const float* em  = (const float*)d_in[0];
    const float* mask = (const float*)d_in[1];
    const float* Wq  = (const float*)d_in[2];
    const float* bq  = (const float*)d_in[3];
    const float* Wk  = (const float*)d_in[4];
    const float* bk  = (const float*)d_in[5];
    const float* Wv  = (const float*)d_in[6];
    const float* bv  = (const float*)d_in[7];
    float* out = (float*)d_out;

    ushort_t* Qb  = (ushort_t*)d_ws;                      // [BH][S][D] bf16, 2MB
    ushort_t* Kb  = Qb + (size_t)BH * SEQ * HEAD;         // 2MB
    ushort_t* Vb  = Kb + (size_t)BH * SEQ * HEAD;         // 2MB
    ushort_t* Vt2 = Vb + (size_t)BH * SEQ * HEAD;         // [BH][64][32d][32s] bf16, 2MB

    qkv_proj<<<dim3(384), dim3(256), 0, stream>>>(em, Wq, bq, Wk, bk, Wv, bv, Qb, Kb, Vb);
    vtrans<<<dim3(512), dim3(256), 0, stream>>>(Vb, Vt2);
    attn<<<dim3(1024), dim3(256), 0, stream>>>(Qb, Kb, Vt2, mask, out);
}

// Round 12
// 69.934 us; speedup vs baseline: 1.1117x; 1.1117x over previous
//
#include <hip/hip_runtime.h>
#include <hip/hip_bf16.h>

typedef float f32x4 __attribute__((ext_vector_type(4)));
typedef float f32x16 __attribute__((ext_vector_type(16)));
typedef __bf16 bf16x8 __attribute__((ext_vector_type(8)));
typedef int v2i __attribute__((ext_vector_type(2)));
typedef unsigned int u32x4 __attribute__((ext_vector_type(4)));
typedef unsigned short ushort_t;

#define SEQ 2048
#define BATCH 2
#define EMS 256
#define NHEAD 8
#define HEAD 32
#define BH (BATCH*NHEAD)
#define LOG2E 1.4426950408889634f
#define QSCALE 0.2550348211f      /* log2(e)/sqrt(32) */
#define THRS 11.5415603f          /* 8*log2(e): defer-max bound e^8 */

static __device__ __forceinline__ ushort_t f2bfbits(float f) {
    unsigned int u = __float_as_uint(f);
    u += 0x7fffu + ((u >> 16) & 1u);
    return (ushort_t)(u >> 16);
}

static __device__ __forceinline__ unsigned cvtpk(float lo, float hi) {
    unsigned r;
    asm("v_cvt_pk_bf16_f32 %0, %1, %2" : "=v"(r) : "v"(lo), "v"(hi));
    return r;
}

static __device__ __forceinline__ float exp2a(float x) {
    float r;
    asm("v_exp_f32 %0, %1" : "=v"(r) : "v"(x));
    return r;
}

static __device__ __forceinline__ bf16x8 cvt8(const float* p) {
    float4 a = *reinterpret_cast<const float4*>(p);
    float4 b = *reinterpret_cast<const float4*>(p + 4);
    union { bf16x8 v; uint4 u; } x;
    x.u.x = cvtpk(a.x, a.y);
    x.u.y = cvtpk(a.z, a.w);
    x.u.z = cvtpk(b.x, b.y);
    x.u.w = cvtpk(b.z, b.w);
    return x.v;
}

// ---------------- Fused pre-pass ----------------
// Blocks [0,2048): FLAT grid-stride mask scan -- 1D addressing, nontemporal
// loads (read-once), 4 independent 16B loads in flight/thread.  Nonzero tiles
// set bits in flagsU via (rare) atomics; all-zero mask never touches flags.
// Blocks [2048,2432): QKV projection (R1 geometry), fills in behind the scan.
__global__ __launch_bounds__(256) void fused_pre(
    const float* __restrict__ em, const float* __restrict__ mask,
    const float* __restrict__ Wq, const float* __restrict__ bq,
    const float* __restrict__ Wk, const float* __restrict__ bk,
    const float* __restrict__ Wv, const float* __restrict__ bv,
    ushort_t* __restrict__ Qb, ushort_t* __restrict__ Kb,
    ushort_t* __restrict__ Vb, unsigned* __restrict__ flagsU)
{
    if (blockIdx.x < 2048) {
        int tid = blockIdx.x * 256 + threadIdx.x;         // 0..524287
        const u32x4* m4 = (const u32x4*)mask;             // 2,097,152 vec4 total
        unsigned nz[4];
        int idx[4];
        #pragma unroll
        for (int i = 0; i < 4; i++) {
            int o = tid + i * 524288;                     // flat float4 index
            u32x4 v = __builtin_nontemporal_load(&m4[o]);
            nz[i] = ((v.x | v.y | v.z | v.w) << 1);       // <<1 kills sign bit
            idx[i] = o;
        }
        #pragma unroll
        for (int i = 0; i < 4; i++) {
            if (nz[i]) {                                  // rare path (nonzero mask)
                int o = idx[i];
                int row = o >> 9;                         // global q-row 0..4095
                int b = row >> 11, q = row & 2047;
                int kt = (o & 511) >> 3;                  // 32-col k-tile 0..63
                int us = (b * 128 + (q >> 4)) * 4 + (kt >> 4);   // ushort index
                atomicOr(flagsU + (us >> 1), (1u << (kt & 15)) << ((us & 1) * 16));
            }
        }
        return;
    }

    // ---- QKV projection: wave = 32 rows x 64 cols of [Q|K|V] (768 cols)
    int wid = (blockIdx.x - 2048) * 4 + (threadIdx.x >> 6);   // < 1536
    int l   = threadIdx.x & 63;
    int l15 = l & 15, lq = l >> 4;
    int rb = wid / 12, cg = wid % 12;
    int r0 = rb * 32, c0 = cg * 64;
    int sel = c0 >> 8;                       // 0=Q 1=K 2=V (uniform per wave)
    const float* W    = sel == 0 ? Wq : (sel == 1 ? Wk : Wv);
    const float* bias = sel == 0 ? bq : (sel == 1 ? bk : bv);
    ushort_t*    dst  = sel == 0 ? Qb : (sel == 1 ? Kb : Vb);
    int cb = c0 & 255;

    f32x4 acc[2][4];
    #pragma unroll
    for (int m = 0; m < 2; m++)
        #pragma unroll
        for (int n = 0; n < 4; n++) acc[m][n] = (f32x4){0.f, 0.f, 0.f, 0.f};

    #pragma unroll
    for (int kk = 0; kk < 8; kk++) {
        int k0 = kk * 32;
        bf16x8 af[2], bfm[4];
        #pragma unroll
        for (int m = 0; m < 2; m++)
            af[m] = cvt8(em + (size_t)(r0 + m * 16 + l15) * EMS + k0 + lq * 8);
        #pragma unroll
        for (int n = 0; n < 4; n++)
            bfm[n] = cvt8(W + (size_t)(cb + n * 16 + l15) * EMS + k0 + lq * 8);
        #pragma unroll
        for (int m = 0; m < 2; m++)
            #pragma unroll
            for (int n = 0; n < 4; n++)
                acc[m][n] = __builtin_amdgcn_mfma_f32_16x16x32_bf16(af[m], bfm[n], acc[m][n], 0, 0, 0);
    }

    float scale = (sel == 0) ? QSCALE : 1.0f;   // log2e/sqrt(D) folded into Q
    #pragma unroll
    for (int m = 0; m < 2; m++) {
        #pragma unroll
        for (int n = 0; n < 4; n++) {
            int c = cb + n * 16 + l15;
            float bv_ = bias[c];
            int h = c >> 5, d = c & 31;
            #pragma unroll
            for (int r = 0; r < 4; r++) {
                int row = r0 + m * 16 + lq * 4 + r;   // C/D: row=(l>>4)*4+reg, col=l&15
                int s = row >> 1, b = row & 1;
                ushort_t v = f2bfbits((acc[m][n][r] + bv_) * scale);
                dst[((size_t)(b * NHEAD + h) * SEQ + s) * HEAD + d] = v;
            }
        }
    }
}

// ---------------- V transpose: [bh][s][d] -> blocked Vt2[bh][kblk][32d][32s]
__global__ __launch_bounds__(256) void vtrans(const ushort_t* __restrict__ Vb,
                                              ushort_t* __restrict__ Vt2)
{
    __shared__ ushort_t t[64][40];      // 80B row stride: 16B-aligned uint4 slots
    int g = blockIdx.x;
    int bh = g & 15, st = g >> 4;       // 32 tiles of 64 s
    int s0 = st * 64;
    int tid = threadIdx.x;

    {
        int sl = tid >> 2, d0 = (tid & 3) * 8;
        uint4 v = *(const uint4*)(Vb + ((size_t)bh * SEQ + s0 + sl) * HEAD + d0);
        *(uint4*)&t[sl][d0] = v;
    }
    __syncthreads();
    {
        int kb_l = tid >> 7, rem = tid & 127;
        int d = rem >> 2, si0 = (rem & 3) * 8;
        union { ushort_t u[8]; uint4 q; } o;
        #pragma unroll
        for (int j = 0; j < 8; j++) o.u[j] = t[kb_l * 32 + si0 + j][d];
        *(uint4*)(Vt2 + (((size_t)bh * 64 + (s0 >> 5) + kb_l) * 32 + d) * 32 + si0) = o.q;
    }
}

// ---------------- Flash attention: 32x32 MFMA, zero-LDS main loop ----------
// Flag-gated mask (R8-proven, ~10us): gathered mask read only for nonzero
// tiles; zero-mask path never touches the mask buffer.
__global__ __launch_bounds__(256, 4) void attn(
    const ushort_t* __restrict__ Qb, const ushort_t* __restrict__ Kb,
    const ushort_t* __restrict__ Vt2, const float* __restrict__ mask,
    const unsigned long long* __restrict__ flagsG, float* __restrict__ out)
{
    int g  = blockIdx.x;
    int qt = g >> 4;              // 0..63 (32-row tiles)
    int b  = (g >> 3) & 1;
    int h  = g & 7;               // h = g mod 8 -> (b,h) pinned per XCD: K/V L2-resident
    int bh = b * NHEAD + h;
    int w  = threadIdx.x >> 6;
    int l  = threadIdx.x & 63;
    int l31 = l & 31, hi = l >> 5;
    int qs0 = qt * 32;

    __shared__ float oacc[4][32][36];
    __shared__ float om[4][32], ol[4][32];

    const ushort_t* qrow = Qb + ((size_t)bh * SEQ + qs0 + l31) * HEAD + hi * 8;
    bf16x8 qf0 = *(const bf16x8*)(qrow);        // d 0..15 fragment
    bf16x8 qf1 = *(const bf16x8*)(qrow + 16);   // d 16..31

    unsigned long long fbits = flagsG[b * 128 + qt * 2] | flagsG[b * 128 + qt * 2 + 1];

    f32x16 acc = {};
    float mrun = -1e30f, lsum = 0.f;            // per-lane, q = l31

    int k0 = w * (SEQ / 4);
    const ushort_t* kbase = Kb  + ((size_t)bh * SEQ + k0 + l31) * HEAD + hi * 8;
    const ushort_t* vbase = Vt2 + ((size_t)bh * 64 + (k0 >> 5)) * 1024 + l31 * 32 + hi * 8;

    bf16x8 kc0 = *(const bf16x8*)(kbase);
    bf16x8 kc1 = *(const bf16x8*)(kbase + 16);
    bf16x8 vc0 = *(const bf16x8*)(vbase);
    bf16x8 vc1 = *(const bf16x8*)(vbase + 16);

    const int NT = (SEQ / 4) / 32;   // 16 tiles per wave
    for (int kt = 0; kt < NT; kt++) {
        int ktn = (kt + 1 < NT) ? kt + 1 : 0;   // wrap: prefetch discarded
        f32x16 st = {};
        st = __builtin_amdgcn_mfma_f32_32x32x16_bf16(kc0, qf0, st, 0, 0, 0);
        st = __builtin_amdgcn_mfma_f32_32x32x16_bf16(kc1, qf1, st, 0, 0, 0);

        bf16x8 kn0 = *(const bf16x8*)(kbase + ktn * 1024);
        bf16x8 kn1 = *(const bf16x8*)(kbase + ktn * 1024 + 16);
        bf16x8 vn0 = *(const bf16x8*)(vbase + ktn * 1024);
        bf16x8 vn1 = *(const bf16x8*)(vbase + ktn * 1024 + 16);

        if ((fbits >> (w * 16 + kt)) & 1ull) {   // nonzero mask tile: rare path
            const float* mr = mask + (size_t)b * SEQ * SEQ
                            + (size_t)(qs0 + l31) * SEQ + k0 + kt * 32 + hi * 4;
            union { float4 f4[4]; float f[16]; } mu;
            mu.f4[0] = *(const float4*)(mr);
            mu.f4[1] = *(const float4*)(mr + 8);
            mu.f4[2] = *(const float4*)(mr + 16);
            mu.f4[3] = *(const float4*)(mr + 24);
            #pragma unroll
            for (int j = 0; j < 16; j++) st[j] = fmaf(mu.f[j], LOG2E, st[j]);
        }

        float x0 = fmaxf(st[0], st[1]),  x1 = fmaxf(st[2], st[3]);
        float x2 = fmaxf(st[4], st[5]),  x3 = fmaxf(st[6], st[7]);
        float x4 = fmaxf(st[8], st[9]),  x5 = fmaxf(st[10], st[11]);
        float x6 = fmaxf(st[12], st[13]), x7 = fmaxf(st[14], st[15]);
        float lmax = fmaxf(fmaxf(fmaxf(x0, x1), fmaxf(x2, x3)),
                           fmaxf(fmaxf(x4, x5), fmaxf(x6, x7)));

        if (__any(lmax > mrun + THRS)) {   // defer-max rescale (rare)
            v2i sw = __builtin_amdgcn_permlane32_swap(
                __float_as_int(lmax), __float_as_int(lmax), false, false);
            float pm = fmaxf(fmaxf(lmax, __int_as_float(sw.x)), __int_as_float(sw.y));
            float nm = fmaxf(mrun, pm);
            float sc = exp2a(mrun - nm);
            lsum *= sc;
            #pragma unroll
            for (int j = 0; j < 16; j++) acc[j] *= sc;   // q = own lane: no shuffle
            mrun = nm;
        }

        float ev[16];
        #pragma unroll
        for (int j = 0; j < 16; j++) ev[j] = exp2a(st[j] - mrun);
        lsum += (((ev[0]+ev[1])+(ev[2]+ev[3])) + ((ev[4]+ev[5])+(ev[6]+ev[7])))
              + (((ev[8]+ev[9])+(ev[10]+ev[11])) + ((ev[12]+ev[13])+(ev[14]+ev[15])));

        unsigned pk[8];
        #pragma unroll
        for (int j = 0; j < 8; j++) pk[j] = cvtpk(ev[2 * j], ev[2 * j + 1]);
        // P^T B-operand repack via permlane32_swap (HW-verified R7):
        v2i p0 = __builtin_amdgcn_permlane32_swap((int)pk[0], (int)pk[2], false, false);
        v2i p1 = __builtin_amdgcn_permlane32_swap((int)pk[1], (int)pk[3], false, false);
        v2i p2 = __builtin_amdgcn_permlane32_swap((int)pk[4], (int)pk[6], false, false);
        v2i p3 = __builtin_amdgcn_permlane32_swap((int)pk[5], (int)pk[7], false, false);
        union { int i[4]; bf16x8 v; } pf0, pf1;
        pf0.i[0] = p0.x; pf0.i[1] = p1.x; pf0.i[2] = p0.y; pf0.i[3] = p1.y;
        pf1.i[0] = p2.x; pf1.i[1] = p3.x; pf1.i[2] = p2.y; pf1.i[3] = p3.y;

        acc = __builtin_amdgcn_mfma_f32_32x32x16_bf16(vc0, pf0.v, acc, 0, 0, 0);
        acc = __builtin_amdgcn_mfma_f32_32x32x16_bf16(vc1, pf1.v, acc, 0, 0, 0);

        kc0 = kn0; kc1 = kn1; vc0 = vn0; vc1 = vn1;
    }

    // lsum across the two half-lanes of each q
    v2i sl = __builtin_amdgcn_permlane32_swap(
        __float_as_int(lsum), __float_as_int(lsum), false, false);
    float lt = __int_as_float(sl.x) + __int_as_float(sl.y);
    if (hi == 0) { om[w][l31] = mrun; ol[w][l31] = lt; }

    #pragma unroll
    for (int gg = 0; gg < 4; gg++) {    // acc reg 4g+j -> d = j + 8g + 4hi
        f32x4 vv = { acc[4*gg], acc[4*gg+1], acc[4*gg+2], acc[4*gg+3] };
        *(f32x4*)&oacc[w][l31][8 * gg + 4 * hi] = vv;
    }
    __syncthreads();

    // merge 4 k-quarters: 1024 outputs, one float4 per thread
    int t = threadIdx.x;
    int q = t >> 3, d4 = (t & 7) * 4;
    float m0 = om[0][q], m1 = om[1][q], m2 = om[2][q], m3 = om[3][q];
    float mg = fmaxf(fmaxf(m0, m1), fmaxf(m2, m3));
    float w0_ = exp2a(m0 - mg), w1_ = exp2a(m1 - mg);
    float w2_ = exp2a(m2 - mg), w3_ = exp2a(m3 - mg);
    float lg = w0_ * ol[0][q] + w1_ * ol[1][q] + w2_ * ol[2][q] + w3_ * ol[3][q];
    float inv = 1.0f / lg;
    float4 o;
    o.x = (w0_*oacc[0][q][d4]   + w1_*oacc[1][q][d4]   + w2_*oacc[2][q][d4]   + w3_*oacc[3][q][d4])   * inv;
    o.y = (w0_*oacc[0][q][d4+1] + w1_*oacc[1][q][d4+1] + w2_*oacc[2][q][d4+1] + w3_*oacc[3][q][d4+1]) * inv;
    o.z = (w0_*oacc[0][q][d4+2] + w1_*oacc[1][q][d4+2] + w2_*oacc[2][q][d4+2] + w3_*oacc[3][q][d4+2]) * inv;
    o.w = (w0_*oacc[0][q][d4+3] + w1_*oacc[1][q][d4+3] + w2_*oacc[2][q][d4+3] + w3_*oacc[3][q][d4+3]) * inv;
    *(float4*)(out + ((size_t)(qs0 + q) * BATCH + b) * EMS + h * HEAD + d4) = o;
}

extern "C" void kernel_launch(void* const* d_in, const int* in_sizes, int n_in,
                              void* d_out, int out_size, void* d_ws, size_t ws_size,
                              hipStream_t stream) {
    const float* em  = (const float*)d_in[0];
    const float* mask = (const float*)d_in[1];
    const float* Wq  = (const float*)d_in[2];
    const float* bq  = (const float*)d_in[3];
    const float* Wk  = (const float*)d_in[4];
    const float* bk  = (const float*)d_in[5];
    const float* Wv  = (const float*)d_in[6];
    const float* bv  = (const float*)d_in[7];
    float* out = (float*)d_out;

    ushort_t* Qb  = (ushort_t*)d_ws;                      // [BH][S][D] bf16, 2MB
    ushort_t* Kb  = Qb + (size_t)BH * SEQ * HEAD;         // 2MB
    ushort_t* Vb  = Kb + (size_t)BH * SEQ * HEAD;         // 2MB
    ushort_t* Vt2 = Vb + (size_t)BH * SEQ * HEAD;         // [BH][64][32d][32s] bf16, 2MB
    unsigned* flagsU = (unsigned*)(Vt2 + (size_t)BH * SEQ * HEAD);  // 2KB

    (void)hipMemsetAsync(flagsU, 0, 2048, stream);
    fused_pre<<<dim3(2432), dim3(256), 0, stream>>>(em, mask, Wq, bq, Wk, bk, Wv, bv,
                                                    Qb, Kb, Vb, flagsU);
    vtrans<<<dim3(512), dim3(256), 0, stream>>>(Vb, Vt2);
    attn<<<dim3(1024), dim3(256), 0, stream>>>(Qb, Kb, Vt2, mask,
                                               (const unsigned long long*)flagsU, out);
}

// Round 13
// 63.124 us; speedup vs baseline: 1.2317x; 1.1079x over previous
//
#include <hip/hip_runtime.h>
#include <hip/hip_bf16.h>

typedef float f32x4 __attribute__((ext_vector_type(4)));
typedef float f32x16 __attribute__((ext_vector_type(16)));
typedef __bf16 bf16x8 __attribute__((ext_vector_type(8)));
typedef int v2i __attribute__((ext_vector_type(2)));
typedef unsigned int u32x4 __attribute__((ext_vector_type(4)));
typedef unsigned short ushort_t;

#define SEQ 2048
#define BATCH 2
#define EMS 256
#define NHEAD 8
#define HEAD 32
#define BH (BATCH*NHEAD)
#define LOG2E 1.4426950408889634f
#define QSCALE 0.2550348211f      /* log2(e)/sqrt(32) */
#define THRS 11.5415603f          /* 8*log2(e): defer-max bound e^8 */

static __device__ __forceinline__ ushort_t f2bfbits(float f) {
    unsigned int u = __float_as_uint(f);
    u += 0x7fffu + ((u >> 16) & 1u);
    return (ushort_t)(u >> 16);
}

static __device__ __forceinline__ unsigned cvtpk(float lo, float hi) {
    unsigned r;
    asm("v_cvt_pk_bf16_f32 %0, %1, %2" : "=v"(r) : "v"(lo), "v"(hi));
    return r;
}

static __device__ __forceinline__ float exp2a(float x) {
    float r;
    asm("v_exp_f32 %0, %1" : "=v"(r) : "v"(x));
    return r;
}

static __device__ __forceinline__ bf16x8 cvt8(const float* p) {
    float4 a = *reinterpret_cast<const float4*>(p);
    float4 b = *reinterpret_cast<const float4*>(p + 4);
    union { bf16x8 v; uint4 u; } x;
    x.u.x = cvtpk(a.x, a.y);
    x.u.y = cvtpk(a.z, a.w);
    x.u.z = cvtpk(b.x, b.y);
    x.u.w = cvtpk(b.z, b.w);
    return x.v;
}

// ---------------- Fused pre-pass: mask scan + QKV(+V-transpose) ------------
// Blocks [0,512): flat nontemporal mask scan, 16 independent 16B loads/thread.
// Blocks [512,896): QKV projection; V written directly in the blocked
// Vt2[bh][kblk][32d][32s] layout (no separate vtrans kernel).
// The qkv compute (~5us) rides inside the scan's read-BW wall for free.
__global__ __launch_bounds__(256) void fused_pre(
    const float* __restrict__ em, const float* __restrict__ mask,
    const float* __restrict__ Wq, const float* __restrict__ bq,
    const float* __restrict__ Wk, const float* __restrict__ bk,
    const float* __restrict__ Wv, const float* __restrict__ bv,
    ushort_t* __restrict__ Qb, ushort_t* __restrict__ Kb,
    ushort_t* __restrict__ Vt2, unsigned* __restrict__ flagsU)
{
    if (blockIdx.x < 512) {
        int gid = blockIdx.x * 256 + threadIdx.x;         // 0..131071
        const u32x4* m4 = (const u32x4*)mask;             // 2,097,152 vec4 total
        unsigned nz[16];
        #pragma unroll
        for (int it = 0; it < 16; it++) {
            int o = gid + it * 131072;
            u32x4 v = __builtin_nontemporal_load(&m4[o]);
            nz[it] = ((v.x | v.y | v.z | v.w) << 1);      // <<1 kills sign bit
        }
        #pragma unroll
        for (int it = 0; it < 16; it++) {
            if (nz[it]) {                                 // rare path (nonzero mask)
                int o = gid + it * 131072;
                int row = o >> 9;                         // global q-row 0..4095
                int b = row >> 11, q = row & 2047;
                int kt = (o & 511) >> 3;                  // 32-col k-tile 0..63
                int us = (b * 128 + (q >> 4)) * 4 + (kt >> 4);   // ushort index
                atomicOr(flagsU + (us >> 1), (1u << (kt & 15)) << ((us & 1) * 16));
            }
        }
        return;
    }

    // ---- QKV projection: wave = 32 rows x 64 cols of [Q|K|V] (768 cols)
    int wid = (blockIdx.x - 512) * 4 + (threadIdx.x >> 6);   // < 1536
    int l   = threadIdx.x & 63;
    int l15 = l & 15, lq = l >> 4;
    int rb = wid / 12, cg = wid % 12;
    int r0 = rb * 32, c0 = cg * 64;
    int sel = c0 >> 8;                       // 0=Q 1=K 2=V (uniform per wave)
    const float* W    = sel == 0 ? Wq : (sel == 1 ? Wk : Wv);
    const float* bias = sel == 0 ? bq : (sel == 1 ? bk : bv);
    int cb = c0 & 255;

    f32x4 acc[2][4];
    #pragma unroll
    for (int m = 0; m < 2; m++)
        #pragma unroll
        for (int n = 0; n < 4; n++) acc[m][n] = (f32x4){0.f, 0.f, 0.f, 0.f};

    #pragma unroll
    for (int kk = 0; kk < 8; kk++) {
        int k0 = kk * 32;
        bf16x8 af[2], bfm[4];
        #pragma unroll
        for (int m = 0; m < 2; m++)
            af[m] = cvt8(em + (size_t)(r0 + m * 16 + l15) * EMS + k0 + lq * 8);
        #pragma unroll
        for (int n = 0; n < 4; n++)
            bfm[n] = cvt8(W + (size_t)(cb + n * 16 + l15) * EMS + k0 + lq * 8);
        #pragma unroll
        for (int m = 0; m < 2; m++)
            #pragma unroll
            for (int n = 0; n < 4; n++)
                acc[m][n] = __builtin_amdgcn_mfma_f32_16x16x32_bf16(af[m], bfm[n], acc[m][n], 0, 0, 0);
    }

    float scale = (sel == 0) ? QSCALE : 1.0f;   // log2e/sqrt(D) folded into Q
    #pragma unroll
    for (int m = 0; m < 2; m++) {
        #pragma unroll
        for (int n = 0; n < 4; n++) {
            int c = cb + n * 16 + l15;
            float bv_ = bias[c];
            int h = c >> 5, d = c & 31;
            #pragma unroll
            for (int r = 0; r < 4; r++) {
                int row = r0 + m * 16 + lq * 4 + r;   // C/D: row=(l>>4)*4+reg, col=l&15
                int s = row >> 1, b = row & 1;
                int bh = b * NHEAD + h;
                ushort_t v = f2bfbits((acc[m][n][r] + bv_) * scale);
                if (sel == 0)      Qb[((size_t)bh * SEQ + s) * HEAD + d] = v;
                else if (sel == 1) Kb[((size_t)bh * SEQ + s) * HEAD + d] = v;
                else               Vt2[(((size_t)bh * 64 + (s >> 5)) * 32 + d) * 32 + (s & 31)] = v;
            }
        }
    }
}

// ---------------- Flash attention: 32x32 MFMA, zero-LDS main loop ----------
// Flag-gated mask (R8/R12-proven): gathered mask read only for nonzero tiles.
__global__ __launch_bounds__(256, 4) void attn(
    const ushort_t* __restrict__ Qb, const ushort_t* __restrict__ Kb,
    const ushort_t* __restrict__ Vt2, const float* __restrict__ mask,
    const unsigned long long* __restrict__ flagsG, float* __restrict__ out)
{
    int g  = blockIdx.x;
    int qt = g >> 4;              // 0..63 (32-row tiles)
    int b  = (g >> 3) & 1;
    int h  = g & 7;               // h = g mod 8 -> (b,h) pinned per XCD: K/V L2-resident
    int bh = b * NHEAD + h;
    int w  = threadIdx.x >> 6;
    int l  = threadIdx.x & 63;
    int l31 = l & 31, hi = l >> 5;
    int qs0 = qt * 32;

    __shared__ float oacc[4][32][36];
    __shared__ float om[4][32], ol[4][32];

    const ushort_t* qrow = Qb + ((size_t)bh * SEQ + qs0 + l31) * HEAD + hi * 8;
    bf16x8 qf0 = *(const bf16x8*)(qrow);        // d 0..15 fragment
    bf16x8 qf1 = *(const bf16x8*)(qrow + 16);   // d 16..31

    unsigned long long fbits = flagsG[b * 128 + qt * 2] | flagsG[b * 128 + qt * 2 + 1];

    f32x16 acc = {};
    float mrun = -1e30f, lsum = 0.f;            // per-lane, q = l31

    int k0 = w * (SEQ / 4);
    const ushort_t* kbase = Kb  + ((size_t)bh * SEQ + k0 + l31) * HEAD + hi * 8;
    const ushort_t* vbase = Vt2 + ((size_t)bh * 64 + (k0 >> 5)) * 1024 + l31 * 32 + hi * 8;

    bf16x8 kc0 = *(const bf16x8*)(kbase);
    bf16x8 kc1 = *(const bf16x8*)(kbase + 16);
    bf16x8 vc0 = *(const bf16x8*)(vbase);
    bf16x8 vc1 = *(const bf16x8*)(vbase + 16);

    const int NT = (SEQ / 4) / 32;   // 16 tiles per wave
    for (int kt = 0; kt < NT; kt++) {
        int ktn = (kt + 1 < NT) ? kt + 1 : 0;   // wrap: prefetch discarded
        f32x16 st = {};
        st = __builtin_amdgcn_mfma_f32_32x32x16_bf16(kc0, qf0, st, 0, 0, 0);
        st = __builtin_amdgcn_mfma_f32_32x32x16_bf16(kc1, qf1, st, 0, 0, 0);

        bf16x8 kn0 = *(const bf16x8*)(kbase + ktn * 1024);
        bf16x8 kn1 = *(const bf16x8*)(kbase + ktn * 1024 + 16);
        bf16x8 vn0 = *(const bf16x8*)(vbase + ktn * 1024);
        bf16x8 vn1 = *(const bf16x8*)(vbase + ktn * 1024 + 16);

        if ((fbits >> (w * 16 + kt)) & 1ull) {   // nonzero mask tile: rare path
            const float* mr = mask + (size_t)b * SEQ * SEQ
                            + (size_t)(qs0 + l31) * SEQ + k0 + kt * 32 + hi * 4;
            union { float4 f4[4]; float f[16]; } mu;
            mu.f4[0] = *(const float4*)(mr);
            mu.f4[1] = *(const float4*)(mr + 8);
            mu.f4[2] = *(const float4*)(mr + 16);
            mu.f4[3] = *(const float4*)(mr + 24);
            #pragma unroll
            for (int j = 0; j < 16; j++) st[j] = fmaf(mu.f[j], LOG2E, st[j]);
        }

        float x0 = fmaxf(st[0], st[1]),  x1 = fmaxf(st[2], st[3]);
        float x2 = fmaxf(st[4], st[5]),  x3 = fmaxf(st[6], st[7]);
        float x4 = fmaxf(st[8], st[9]),  x5 = fmaxf(st[10], st[11]);
        float x6 = fmaxf(st[12], st[13]), x7 = fmaxf(st[14], st[15]);
        float lmax = fmaxf(fmaxf(fmaxf(x0, x1), fmaxf(x2, x3)),
                           fmaxf(fmaxf(x4, x5), fmaxf(x6, x7)));

        if (__any(lmax > mrun + THRS)) {   // defer-max rescale (rare)
            v2i sw = __builtin_amdgcn_permlane32_swap(
                __float_as_int(lmax), __float_as_int(lmax), false, false);
            float pm = fmaxf(fmaxf(lmax, __int_as_float(sw.x)), __int_as_float(sw.y));
            float nm = fmaxf(mrun, pm);
            float sc = exp2a(mrun - nm);
            lsum *= sc;
            #pragma unroll
            for (int j = 0; j < 16; j++) acc[j] *= sc;   // q = own lane: no shuffle
            mrun = nm;
        }

        float ev[16];
        #pragma unroll
        for (int j = 0; j < 16; j++) ev[j] = exp2a(st[j] - mrun);
        lsum += (((ev[0]+ev[1])+(ev[2]+ev[3])) + ((ev[4]+ev[5])+(ev[6]+ev[7])))
              + (((ev[8]+ev[9])+(ev[10]+ev[11])) + ((ev[12]+ev[13])+(ev[14]+ev[15])));

        unsigned pk[8];
        #pragma unroll
        for (int j = 0; j < 8; j++) pk[j] = cvtpk(ev[2 * j], ev[2 * j + 1]);
        // P^T B-operand repack via permlane32_swap (HW-verified R7):
        v2i p0 = __builtin_amdgcn_permlane32_swap((int)pk[0], (int)pk[2], false, false);
        v2i p1 = __builtin_amdgcn_permlane32_swap((int)pk[1], (int)pk[3], false, false);
        v2i p2 = __builtin_amdgcn_permlane32_swap((int)pk[4], (int)pk[6], false, false);
        v2i p3 = __builtin_amdgcn_permlane32_swap((int)pk[5], (int)pk[7], false, false);
        union { int i[4]; bf16x8 v; } pf0, pf1;
        pf0.i[0] = p0.x; pf0.i[1] = p1.x; pf0.i[2] = p0.y; pf0.i[3] = p1.y;
        pf1.i[0] = p2.x; pf1.i[1] = p3.x; pf1.i[2] = p2.y; pf1.i[3] = p3.y;

        acc = __builtin_amdgcn_mfma_f32_32x32x16_bf16(vc0, pf0.v, acc, 0, 0, 0);
        acc = __builtin_amdgcn_mfma_f32_32x32x16_bf16(vc1, pf1.v, acc, 0, 0, 0);

        kc0 = kn0; kc1 = kn1; vc0 = vn0; vc1 = vn1;
    }

    // lsum across the two half-lanes of each q
    v2i sl = __builtin_amdgcn_permlane32_swap(
        __float_as_int(lsum), __float_as_int(lsum), false, false);
    float lt = __int_as_float(sl.x) + __int_as_float(sl.y);
    if (hi == 0) { om[w][l31] = mrun; ol[w][l31] = lt; }

    #pragma unroll
    for (int gg = 0; gg < 4; gg++) {    // acc reg 4g+j -> d = j + 8g + 4hi
        f32x4 vv = { acc[4*gg], acc[4*gg+1], acc[4*gg+2], acc[4*gg+3] };
        *(f32x4*)&oacc[w][l31][8 * gg + 4 * hi] = vv;
    }
    __syncthreads();

    // merge 4 k-quarters: 1024 outputs, one float4 per thread
    int t = threadIdx.x;
    int q = t >> 3, d4 = (t & 7) * 4;
    float m0 = om[0][q], m1 = om[1][q], m2 = om[2][q], m3 = om[3][q];
    float mg = fmaxf(fmaxf(m0, m1), fmaxf(m2, m3));
    float w0_ = exp2a(m0 - mg), w1_ = exp2a(m1 - mg);
    float w2_ = exp2a(m2 - mg), w3_ = exp2a(m3 - mg);
    float lg = w0_ * ol[0][q] + w1_ * ol[1][q] + w2_ * ol[2][q] + w3_ * ol[3][q];
    float inv = 1.0f / lg;
    float4 o;
    o.x = (w0_*oacc[0][q][d4]   + w1_*oacc[1][q][d4]   + w2_*oacc[2][q][d4]   + w3_*oacc[3][q][d4])   * inv;
    o.y = (w0_*oacc[0][q][d4+1] + w1_*oacc[1][q][d4+1] + w2_*oacc[2][q][d4+1] + w3_*oacc[3][q][d4+1]) * inv;
    o.z = (w0_*oacc[0][q][d4+2] + w1_*oacc[1][q][d4+2] + w2_*oacc[2][q][d4+2] + w3_*oacc[3][q][d4+2]) * inv;
    o.w = (w0_*oacc[0][q][d4+3] + w1_*oacc[1][q][d4+3] + w2_*oacc[2][q][d4+3] + w3_*oacc[3][q][d4+3]) * inv;
    *(float4*)(out + ((size_t)(qs0 + q) * BATCH + b) * EMS + h * HEAD + d4) = o;
}

extern "C" void kernel_launch(void* const* d_in, const int* in_sizes, int n_in,
                              void* d_out, int out_size, void* d_ws, size_t ws_size,
                              hipStream_t stream) {
    const float* em  = (const float*)d_in[0];
    const float* mask = (const float*)d_in[1];
    const float* Wq  = (const float*)d_in[2];
    const float* bq  = (const float*)d_in[3];
    const float* Wk  = (const float*)d_in[4];
    const float* bk  = (const float*)d_in[5];
    const float* Wv  = (const float*)d_in[6];
    const float* bv  = (const float*)d_in[7];
    float* out = (float*)d_out;

    ushort_t* Qb  = (ushort_t*)d_ws;                      // [BH][S][D] bf16, 2MB
    ushort_t* Kb  = Qb + (size_t)BH * SEQ * HEAD;         // 2MB
    ushort_t* Vt2 = Kb + (size_t)BH * SEQ * HEAD;         // [BH][64][32d][32s] bf16, 2MB
    unsigned* flagsU = (unsigned*)(Vt2 + (size_t)BH * SEQ * HEAD);  // 2KB

    (void)hipMemsetAsync(flagsU, 0, 2048, stream);
    fused_pre<<<dim3(896), dim3(256), 0, stream>>>(em, mask, Wq, bq, Wk, bk, Wv, bv,
                                                   Qb, Kb, Vt2, flagsU);
    attn<<<dim3(1024), dim3(256), 0, stream>>>(Qb, Kb, Vt2, mask,
                                               (const unsigned long long*)flagsU, out);
}

// Round 14
// 63.057 us; speedup vs baseline: 1.2330x; 1.0011x over previous
//
#include <hip/hip_runtime.h>
#include <hip/hip_bf16.h>

typedef float f32x4 __attribute__((ext_vector_type(4)));
typedef float f32x16 __attribute__((ext_vector_type(16)));
typedef __bf16 bf16x8 __attribute__((ext_vector_type(8)));
typedef int v2i __attribute__((ext_vector_type(2)));
typedef unsigned int u32x4 __attribute__((ext_vector_type(4)));
typedef unsigned short ushort_t;

#define SEQ 2048
#define BATCH 2
#define EMS 256
#define NHEAD 8
#define HEAD 32
#define BH (BATCH*NHEAD)
#define LOG2E 1.4426950408889634f
#define QSCALE 0.2550348211f      /* log2(e)/sqrt(32) */
#define THRS 11.5415603f          /* 8*log2(e): defer-max bound e^8 */
#define MASKF (BATCH*SEQ*SEQ)     /* mask floats: 8,388,608 (33.5 MB) */

static __device__ __forceinline__ ushort_t f2bfbits(float f) {
    unsigned int u = __float_as_uint(f);
    u += 0x7fffu + ((u >> 16) & 1u);
    return (ushort_t)(u >> 16);
}

static __device__ __forceinline__ unsigned cvtpk(float lo, float hi) {
    unsigned r;
    asm("v_cvt_pk_bf16_f32 %0, %1, %2" : "=v"(r) : "v"(lo), "v"(hi));
    return r;
}

static __device__ __forceinline__ float exp2a(float x) {
    float r;
    asm("v_exp_f32 %0, %1" : "=v"(r) : "v"(x));
    return r;
}

static __device__ __forceinline__ bf16x8 cvt8(const float* p) {
    float4 a = *reinterpret_cast<const float4*>(p);
    float4 b = *reinterpret_cast<const float4*>(p + 4);
    union { bf16x8 v; uint4 u; } x;
    x.u.x = cvtpk(a.x, a.y);
    x.u.y = cvtpk(a.z, a.w);
    x.u.z = cvtpk(b.x, b.y);
    x.u.w = cvtpk(b.z, b.w);
    return x.v;
}

// ---------------- Fused pre-pass: QKV(+V-transpose) + mask scan ------------
// Blocks [0,384): QKV projection; V written directly in blocked
// Vt2[bh][kblk][32d][32s] layout.
// Blocks [384,896): mask scan reading the d_ws COPY of the mask (d_in reads
// are walled at ~1TB/s in this env; d_ws reads are multi-TB/s).
__global__ __launch_bounds__(256) void fused_pre(
    const float* __restrict__ em, const float* __restrict__ maskC,
    const float* __restrict__ Wq, const float* __restrict__ bq,
    const float* __restrict__ Wk, const float* __restrict__ bk,
    const float* __restrict__ Wv, const float* __restrict__ bv,
    ushort_t* __restrict__ Qb, ushort_t* __restrict__ Kb,
    ushort_t* __restrict__ Vt2, unsigned* __restrict__ flagsU)
{
    if (blockIdx.x >= 384) {
        int gid = (blockIdx.x - 384) * 256 + threadIdx.x;  // 0..131071
        const u32x4* m4 = (const u32x4*)maskC;             // 2,097,152 vec4 total
        unsigned nz[16];
        #pragma unroll
        for (int it = 0; it < 16; it++) {
            int o = gid + it * 131072;
            u32x4 v = m4[o];
            nz[it] = ((v.x | v.y | v.z | v.w) << 1);       // <<1 kills sign bit
        }
        #pragma unroll
        for (int it = 0; it < 16; it++) {
            if (nz[it]) {                                  // rare path (nonzero mask)
                int o = gid + it * 131072;
                int row = o >> 9;                          // global q-row 0..4095
                int b = row >> 11, q = row & 2047;
                int kt = (o & 511) >> 3;                   // 32-col k-tile 0..63
                int us = (b * 128 + (q >> 4)) * 4 + (kt >> 4);   // ushort index
                atomicOr(flagsU + (us >> 1), (1u << (kt & 15)) << ((us & 1) * 16));
            }
        }
        return;
    }

    // ---- QKV projection: wave = 32 rows x 64 cols of [Q|K|V] (768 cols)
    int wid = blockIdx.x * 4 + (threadIdx.x >> 6);   // < 1536
    int l   = threadIdx.x & 63;
    int l15 = l & 15, lq = l >> 4;
    int rb = wid / 12, cg = wid % 12;
    int r0 = rb * 32, c0 = cg * 64;
    int sel = c0 >> 8;                       // 0=Q 1=K 2=V (uniform per wave)
    const float* W    = sel == 0 ? Wq : (sel == 1 ? Wk : Wv);
    const float* bias = sel == 0 ? bq : (sel == 1 ? bk : bv);
    int cb = c0 & 255;

    f32x4 acc[2][4];
    #pragma unroll
    for (int m = 0; m < 2; m++)
        #pragma unroll
        for (int n = 0; n < 4; n++) acc[m][n] = (f32x4){0.f, 0.f, 0.f, 0.f};

    #pragma unroll
    for (int kk = 0; kk < 8; kk++) {
        int k0 = kk * 32;
        bf16x8 af[2], bfm[4];
        #pragma unroll
        for (int m = 0; m < 2; m++)
            af[m] = cvt8(em + (size_t)(r0 + m * 16 + l15) * EMS + k0 + lq * 8);
        #pragma unroll
        for (int n = 0; n < 4; n++)
            bfm[n] = cvt8(W + (size_t)(cb + n * 16 + l15) * EMS + k0 + lq * 8);
        #pragma unroll
        for (int m = 0; m < 2; m++)
            #pragma unroll
            for (int n = 0; n < 4; n++)
                acc[m][n] = __builtin_amdgcn_mfma_f32_16x16x32_bf16(af[m], bfm[n], acc[m][n], 0, 0, 0);
    }

    float scale = (sel == 0) ? QSCALE : 1.0f;   // log2e/sqrt(D) folded into Q
    #pragma unroll
    for (int m = 0; m < 2; m++) {
        #pragma unroll
        for (int n = 0; n < 4; n++) {
            int c = cb + n * 16 + l15;
            float bv_ = bias[c];
            int h = c >> 5, d = c & 31;
            #pragma unroll
            for (int r = 0; r < 4; r++) {
                int row = r0 + m * 16 + lq * 4 + r;   // C/D: row=(l>>4)*4+reg, col=l&15
                int s = row >> 1, b = row & 1;
                int bh = b * NHEAD + h;
                ushort_t v = f2bfbits((acc[m][n][r] + bv_) * scale);
                if (sel == 0)      Qb[((size_t)bh * SEQ + s) * HEAD + d] = v;
                else if (sel == 1) Kb[((size_t)bh * SEQ + s) * HEAD + d] = v;
                else               Vt2[(((size_t)bh * 64 + (s >> 5)) * 32 + d) * 32 + (s & 31)] = v;
            }
        }
    }
}

// ---------------- Flash attention: 32x32 MFMA, zero-LDS main loop ----------
// Flag-gated mask; rare path reads the d_ws mask copy.
__global__ __launch_bounds__(256, 4) void attn(
    const ushort_t* __restrict__ Qb, const ushort_t* __restrict__ Kb,
    const ushort_t* __restrict__ Vt2, const float* __restrict__ maskC,
    const unsigned long long* __restrict__ flagsG, float* __restrict__ out)
{
    int g  = blockIdx.x;
    int qt = g >> 4;              // 0..63 (32-row tiles)
    int b  = (g >> 3) & 1;
    int h  = g & 7;               // h = g mod 8 -> (b,h) pinned per XCD: K/V L2-resident
    int bh = b * NHEAD + h;
    int w  = threadIdx.x >> 6;
    int l  = threadIdx.x & 63;
    int l31 = l & 31, hi = l >> 5;
    int qs0 = qt * 32;

    __shared__ float oacc[4][32][36];
    __shared__ float om[4][32], ol[4][32];

    const ushort_t* qrow = Qb + ((size_t)bh * SEQ + qs0 + l31) * HEAD + hi * 8;
    bf16x8 qf0 = *(const bf16x8*)(qrow);        // d 0..15 fragment
    bf16x8 qf1 = *(const bf16x8*)(qrow + 16);   // d 16..31

    unsigned long long fbits = flagsG[b * 128 + qt * 2] | flagsG[b * 128 + qt * 2 + 1];

    f32x16 acc = {};
    float mrun = -1e30f, lsum = 0.f;            // per-lane, q = l31

    int k0 = w * (SEQ / 4);
    const ushort_t* kbase = Kb  + ((size_t)bh * SEQ + k0 + l31) * HEAD + hi * 8;
    const ushort_t* vbase = Vt2 + ((size_t)bh * 64 + (k0 >> 5)) * 1024 + l31 * 32 + hi * 8;

    bf16x8 kc0 = *(const bf16x8*)(kbase);
    bf16x8 kc1 = *(const bf16x8*)(kbase + 16);
    bf16x8 vc0 = *(const bf16x8*)(vbase);
    bf16x8 vc1 = *(const bf16x8*)(vbase + 16);

    const int NT = (SEQ / 4) / 32;   // 16 tiles per wave
    for (int kt = 0; kt < NT; kt++) {
        int ktn = (kt + 1 < NT) ? kt + 1 : 0;   // wrap: prefetch discarded
        f32x16 st = {};
        st = __builtin_amdgcn_mfma_f32_32x32x16_bf16(kc0, qf0, st, 0, 0, 0);
        st = __builtin_amdgcn_mfma_f32_32x32x16_bf16(kc1, qf1, st, 0, 0, 0);

        bf16x8 kn0 = *(const bf16x8*)(kbase + ktn * 1024);
        bf16x8 kn1 = *(const bf16x8*)(kbase + ktn * 1024 + 16);
        bf16x8 vn0 = *(const bf16x8*)(vbase + ktn * 1024);
        bf16x8 vn1 = *(const bf16x8*)(vbase + ktn * 1024 + 16);

        if ((fbits >> (w * 16 + kt)) & 1ull) {   // nonzero mask tile: rare path
            const float* mr = maskC + (size_t)b * SEQ * SEQ
                            + (size_t)(qs0 + l31) * SEQ + k0 + kt * 32 + hi * 4;
            union { float4 f4[4]; float f[16]; } mu;
            mu.f4[0] = *(const float4*)(mr);
            mu.f4[1] = *(const float4*)(mr + 8);
            mu.f4[2] = *(const float4*)(mr + 16);
            mu.f4[3] = *(const float4*)(mr + 24);
            #pragma unroll
            for (int j = 0; j < 16; j++) st[j] = fmaf(mu.f[j], LOG2E, st[j]);
        }

        float x0 = fmaxf(st[0], st[1]),  x1 = fmaxf(st[2], st[3]);
        float x2 = fmaxf(st[4], st[5]),  x3 = fmaxf(st[6], st[7]);
        float x4 = fmaxf(st[8], st[9]),  x5 = fmaxf(st[10], st[11]);
        float x6 = fmaxf(st[12], st[13]), x7 = fmaxf(st[14], st[15]);
        float lmax = fmaxf(fmaxf(fmaxf(x0, x1), fmaxf(x2, x3)),
                           fmaxf(fmaxf(x4, x5), fmaxf(x6, x7)));

        if (__any(lmax > mrun + THRS)) {   // defer-max rescale (rare)
            v2i sw = __builtin_amdgcn_permlane32_swap(
                __float_as_int(lmax), __float_as_int(lmax), false, false);
            float pm = fmaxf(fmaxf(lmax, __int_as_float(sw.x)), __int_as_float(sw.y));
            float nm = fmaxf(mrun, pm);
            float sc = exp2a(mrun - nm);
            lsum *= sc;
            #pragma unroll
            for (int j = 0; j < 16; j++) acc[j] *= sc;   // q = own lane: no shuffle
            mrun = nm;
        }

        float ev[16];
        #pragma unroll
        for (int j = 0; j < 16; j++) ev[j] = exp2a(st[j] - mrun);
        lsum += (((ev[0]+ev[1])+(ev[2]+ev[3])) + ((ev[4]+ev[5])+(ev[6]+ev[7])))
              + (((ev[8]+ev[9])+(ev[10]+ev[11])) + ((ev[12]+ev[13])+(ev[14]+ev[15])));

        unsigned pk[8];
        #pragma unroll
        for (int j = 0; j < 8; j++) pk[j] = cvtpk(ev[2 * j], ev[2 * j + 1]);
        // P^T B-operand repack via permlane32_swap (HW-verified R7):
        v2i p0 = __builtin_amdgcn_permlane32_swap((int)pk[0], (int)pk[2], false, false);
        v2i p1 = __builtin_amdgcn_permlane32_swap((int)pk[1], (int)pk[3], false, false);
        v2i p2 = __builtin_amdgcn_permlane32_swap((int)pk[4], (int)pk[6], false, false);
        v2i p3 = __builtin_amdgcn_permlane32_swap((int)pk[5], (int)pk[7], false, false);
        union { int i[4]; bf16x8 v; } pf0, pf1;
        pf0.i[0] = p0.x; pf0.i[1] = p1.x; pf0.i[2] = p0.y; pf0.i[3] = p1.y;
        pf1.i[0] = p2.x; pf1.i[1] = p3.x; pf1.i[2] = p2.y; pf1.i[3] = p3.y;

        acc = __builtin_amdgcn_mfma_f32_32x32x16_bf16(vc0, pf0.v, acc, 0, 0, 0);
        acc = __builtin_amdgcn_mfma_f32_32x32x16_bf16(vc1, pf1.v, acc, 0, 0, 0);

        kc0 = kn0; kc1 = kn1; vc0 = vn0; vc1 = vn1;
    }

    // lsum across the two half-lanes of each q
    v2i sl = __builtin_amdgcn_permlane32_swap(
        __float_as_int(lsum), __float_as_int(lsum), false, false);
    float lt = __int_as_float(sl.x) + __int_as_float(sl.y);
    if (hi == 0) { om[w][l31] = mrun; ol[w][l31] = lt; }

    #pragma unroll
    for (int gg = 0; gg < 4; gg++) {    // acc reg 4g+j -> d = j + 8g + 4hi
        f32x4 vv = { acc[4*gg], acc[4*gg+1], acc[4*gg+2], acc[4*gg+3] };
        *(f32x4*)&oacc[w][l31][8 * gg + 4 * hi] = vv;
    }
    __syncthreads();

    // merge 4 k-quarters: 1024 outputs, one float4 per thread
    int t = threadIdx.x;
    int q = t >> 3, d4 = (t & 7) * 4;
    float m0 = om[0][q], m1 = om[1][q], m2 = om[2][q], m3 = om[3][q];
    float mg = fmaxf(fmaxf(m0, m1), fmaxf(m2, m3));
    float w0_ = exp2a(m0 - mg), w1_ = exp2a(m1 - mg);
    float w2_ = exp2a(m2 - mg), w3_ = exp2a(m3 - mg);
    float lg = w0_ * ol[0][q] + w1_ * ol[1][q] + w2_ * ol[2][q] + w3_ * ol[3][q];
    float inv = 1.0f / lg;
    float4 o;
    o.x = (w0_*oacc[0][q][d4]   + w1_*oacc[1][q][d4]   + w2_*oacc[2][q][d4]   + w3_*oacc[3][q][d4])   * inv;
    o.y = (w0_*oacc[0][q][d4+1] + w1_*oacc[1][q][d4+1] + w2_*oacc[2][q][d4+1] + w3_*oacc[3][q][d4+1]) * inv;
    o.z = (w0_*oacc[0][q][d4+2] + w1_*oacc[1][q][d4+2] + w2_*oacc[2][q][d4+2] + w3_*oacc[3][q][d4+2]) * inv;
    o.w = (w0_*oacc[0][q][d4+3] + w1_*oacc[1][q][d4+3] + w2_*oacc[2][q][d4+3] + w3_*oacc[3][q][d4+3]) * inv;
    *(float4*)(out + ((size_t)(qs0 + q) * BATCH + b) * EMS + h * HEAD + d4) = o;
}

extern "C" void kernel_launch(void* const* d_in, const int* in_sizes, int n_in,
                              void* d_out, int out_size, void* d_ws, size_t ws_size,
                              hipStream_t stream) {
    const float* em  = (const float*)d_in[0];
    const float* mask = (const float*)d_in[1];
    const float* Wq  = (const float*)d_in[2];
    const float* bq  = (const float*)d_in[3];
    const float* Wk  = (const float*)d_in[4];
    const float* bk  = (const float*)d_in[5];
    const float* Wv  = (const float*)d_in[6];
    const float* bv  = (const float*)d_in[7];
    float* out = (float*)d_out;

    ushort_t* Qb  = (ushort_t*)d_ws;                      // [BH][S][D] bf16, 2MB
    ushort_t* Kb  = Qb + (size_t)BH * SEQ * HEAD;         // 2MB
    ushort_t* Vt2 = Kb + (size_t)BH * SEQ * HEAD;         // [BH][64][32d][32s] bf16, 2MB
    unsigned* flagsU = (unsigned*)(Vt2 + (size_t)BH * SEQ * HEAD);  // 2KB
    float* maskC = (float*)((char*)d_ws + 8 * 1024 * 1024);         // 33.5MB copy

    // DMA the mask out of the slow d_in allocation into d_ws (different HW
    // path than VMEM reads -- the experiment of this round).
    (void)hipMemcpyAsync(maskC, mask, (size_t)MASKF * 4, hipMemcpyDeviceToDevice, stream);
    (void)hipMemsetAsync(flagsU, 0, 2048, stream);
    fused_pre<<<dim3(896), dim3(256), 0, stream>>>(em, maskC, Wq, bq, Wk, bk, Wv, bv,
                                                   Qb, Kb, Vt2, flagsU);
    attn<<<dim3(1024), dim3(256), 0, stream>>>(Qb, Kb, Vt2, maskC,
                                               (const unsigned long long*)flagsU, out);
}

// Round 15
// 52.916 us; speedup vs baseline: 1.4693x; 1.1916x over previous
//
#include <hip/hip_runtime.h>
#include <hip/hip_bf16.h>

typedef float f32x4 __attribute__((ext_vector_type(4)));
typedef float f32x16 __attribute__((ext_vector_type(16)));
typedef __bf16 bf16x8 __attribute__((ext_vector_type(8)));
typedef int v2i __attribute__((ext_vector_type(2)));
typedef unsigned short ushort_t;

#define SEQ 2048
#define BATCH 2
#define EMS 256
#define NHEAD 8
#define HEAD 32
#define BH (BATCH*NHEAD)
#define LOG2E 1.4426950408889634f
#define QSCALE 0.2550348211f      /* log2(e)/sqrt(32) */
#define THRS 11.5415603f          /* 8*log2(e): defer-max bound e^8 */

static __device__ __forceinline__ ushort_t f2bfbits(float f) {
    unsigned int u = __float_as_uint(f);
    u += 0x7fffu + ((u >> 16) & 1u);
    return (ushort_t)(u >> 16);
}

static __device__ __forceinline__ unsigned cvtpk(float lo, float hi) {
    unsigned r;
    asm("v_cvt_pk_bf16_f32 %0, %1, %2" : "=v"(r) : "v"(lo), "v"(hi));
    return r;
}

static __device__ __forceinline__ float exp2a(float x) {
    float r;
    asm("v_exp_f32 %0, %1" : "=v"(r) : "v"(x));
    return r;
}

static __device__ __forceinline__ bf16x8 cvt8(const float* p) {
    float4 a = *reinterpret_cast<const float4*>(p);
    float4 b = *reinterpret_cast<const float4*>(p + 4);
    union { bf16x8 v; uint4 u; } x;
    x.u.x = cvtpk(a.x, a.y);
    x.u.y = cvtpk(a.z, a.w);
    x.u.z = cvtpk(b.x, b.y);
    x.u.w = cvtpk(b.z, b.w);
    return x.v;
}

// ---------------- Fused pre-pass: QKV(+V-transpose) + mask scan ------------
// Blocks [0,384): QKV projection (R1 geometry); V written directly in blocked
// Vt2[bh][kblk][32d][32s] layout (no separate vtrans kernel).
// Blocks [384,896): mask scan, R8's measured-best pattern: block = (b, qt16,
// khalf) covering 16 rows x 1024 cols, 1KB contiguous per wave-instruction.
// Every flag word is written unconditionally (no memset needed).
// d_in reads are environment-walled at ~1TB/s (R5..R14, incl. DMA blit);
// this kernel's duration ~= 38.3MB / wall and the qkv work rides inside.
__global__ __launch_bounds__(256) void fused_pre(
    const float* __restrict__ em, const float* __restrict__ mask,
    const float* __restrict__ Wq, const float* __restrict__ bq,
    const float* __restrict__ Wk, const float* __restrict__ bk,
    const float* __restrict__ Wv, const float* __restrict__ bv,
    ushort_t* __restrict__ Qb, ushort_t* __restrict__ Kb,
    ushort_t* __restrict__ Vt2, unsigned* __restrict__ flagsU)
{
    if (blockIdx.x >= 384) {
        // ---- mask scan: block = (b, qt16, khalf): 16 rows x 1024 cols
        int sb = blockIdx.x - 384;                        // < 512
        int kh = sb & 1, qt = (sb >> 1) & 127, b = sb >> 8;
        int t = threadIdx.x;
        const float* base = mask + ((size_t)b * SEQ + qt * 16) * SEQ + kh * 1024 + t * 4;
        unsigned nz = 0;
        #pragma unroll 4
        for (int it = 0; it < 16; it++) {
            float4 v = *(const float4*)(base + (size_t)it * SEQ);
            unsigned u = (__float_as_uint(v.x) | __float_as_uint(v.y) |
                          __float_as_uint(v.z) | __float_as_uint(v.w)) << 1;  // kill sign
            if (u) nz = 1;
        }
        __shared__ unsigned fl;
        if (t == 0) fl = 0;
        __syncthreads();
        if (nz) atomicOr(&fl, 1u << (t >> 3));            // 8 threads per 32-col tile
        __syncthreads();
        if (t == 0) flagsU[(b * 128 + qt) * 2 + kh] = fl; // covers ALL words
        return;
    }

    // ---- QKV projection: wave = 32 rows x 64 cols of [Q|K|V] (768 cols)
    int wid = blockIdx.x * 4 + (threadIdx.x >> 6);   // < 1536
    int l   = threadIdx.x & 63;
    int l15 = l & 15, lq = l >> 4;
    int rb = wid / 12, cg = wid % 12;
    int r0 = rb * 32, c0 = cg * 64;
    int sel = c0 >> 8;                       // 0=Q 1=K 2=V (uniform per wave)
    const float* W    = sel == 0 ? Wq : (sel == 1 ? Wk : Wv);
    const float* bias = sel == 0 ? bq : (sel == 1 ? bk : bv);
    int cb = c0 & 255;

    f32x4 acc[2][4];
    #pragma unroll
    for (int m = 0; m < 2; m++)
        #pragma unroll
        for (int n = 0; n < 4; n++) acc[m][n] = (f32x4){0.f, 0.f, 0.f, 0.f};

    #pragma unroll
    for (int kk = 0; kk < 8; kk++) {
        int k0 = kk * 32;
        bf16x8 af[2], bfm[4];
        #pragma unroll
        for (int m = 0; m < 2; m++)
            af[m] = cvt8(em + (size_t)(r0 + m * 16 + l15) * EMS + k0 + lq * 8);
        #pragma unroll
        for (int n = 0; n < 4; n++)
            bfm[n] = cvt8(W + (size_t)(cb + n * 16 + l15) * EMS + k0 + lq * 8);
        #pragma unroll
        for (int m = 0; m < 2; m++)
            #pragma unroll
            for (int n = 0; n < 4; n++)
                acc[m][n] = __builtin_amdgcn_mfma_f32_16x16x32_bf16(af[m], bfm[n], acc[m][n], 0, 0, 0);
    }

    float scale = (sel == 0) ? QSCALE : 1.0f;   // log2e/sqrt(D) folded into Q
    #pragma unroll
    for (int m = 0; m < 2; m++) {
        #pragma unroll
        for (int n = 0; n < 4; n++) {
            int c = cb + n * 16 + l15;
            float bv_ = bias[c];
            int h = c >> 5, d = c & 31;
            #pragma unroll
            for (int r = 0; r < 4; r++) {
                int row = r0 + m * 16 + lq * 4 + r;   // C/D: row=(l>>4)*4+reg, col=l&15
                int s = row >> 1, b = row & 1;
                int bh = b * NHEAD + h;
                ushort_t v = f2bfbits((acc[m][n][r] + bv_) * scale);
                if (sel == 0)      Qb[((size_t)bh * SEQ + s) * HEAD + d] = v;
                else if (sel == 1) Kb[((size_t)bh * SEQ + s) * HEAD + d] = v;
                else               Vt2[(((size_t)bh * 64 + (s >> 5)) * 32 + d) * 32 + (s & 31)] = v;
            }
        }
    }
}

// ---------------- Flash attention: 32x32 MFMA, zero-LDS main loop ----------
// Flag-gated mask (R8/R12-proven): gathered mask read only for nonzero tiles.
__global__ __launch_bounds__(256, 4) void attn(
    const ushort_t* __restrict__ Qb, const ushort_t* __restrict__ Kb,
    const ushort_t* __restrict__ Vt2, const float* __restrict__ mask,
    const unsigned long long* __restrict__ flagsG, float* __restrict__ out)
{
    int g  = blockIdx.x;
    int qt = g >> 4;              // 0..63 (32-row tiles)
    int b  = (g >> 3) & 1;
    int h  = g & 7;               // h = g mod 8 -> (b,h) pinned per XCD: K/V L2-resident
    int bh = b * NHEAD + h;
    int w  = threadIdx.x >> 6;
    int l  = threadIdx.x & 63;
    int l31 = l & 31, hi = l >> 5;
    int qs0 = qt * 32;

    __shared__ float oacc[4][32][36];
    __shared__ float om[4][32], ol[4][32];

    const ushort_t* qrow = Qb + ((size_t)bh * SEQ + qs0 + l31) * HEAD + hi * 8;
    bf16x8 qf0 = *(const bf16x8*)(qrow);        // d 0..15 fragment
    bf16x8 qf1 = *(const bf16x8*)(qrow + 16);   // d 16..31

    unsigned long long fbits = flagsG[b * 128 + qt * 2] | flagsG[b * 128 + qt * 2 + 1];

    f32x16 acc = {};
    float mrun = -1e30f, lsum = 0.f;            // per-lane, q = l31

    int k0 = w * (SEQ / 4);
    const ushort_t* kbase = Kb  + ((size_t)bh * SEQ + k0 + l31) * HEAD + hi * 8;
    const ushort_t* vbase = Vt2 + ((size_t)bh * 64 + (k0 >> 5)) * 1024 + l31 * 32 + hi * 8;

    bf16x8 kc0 = *(const bf16x8*)(kbase);
    bf16x8 kc1 = *(const bf16x8*)(kbase + 16);
    bf16x8 vc0 = *(const bf16x8*)(vbase);
    bf16x8 vc1 = *(const bf16x8*)(vbase + 16);

    const int NT = (SEQ / 4) / 32;   // 16 tiles per wave
    for (int kt = 0; kt < NT; kt++) {
        int ktn = (kt + 1 < NT) ? kt + 1 : 0;   // wrap: prefetch discarded
        f32x16 st = {};
        st = __builtin_amdgcn_mfma_f32_32x32x16_bf16(kc0, qf0, st, 0, 0, 0);
        st = __builtin_amdgcn_mfma_f32_32x32x16_bf16(kc1, qf1, st, 0, 0, 0);

        bf16x8 kn0 = *(const bf16x8*)(kbase + ktn * 1024);
        bf16x8 kn1 = *(const bf16x8*)(kbase + ktn * 1024 + 16);
        bf16x8 vn0 = *(const bf16x8*)(vbase + ktn * 1024);
        bf16x8 vn1 = *(const bf16x8*)(vbase + ktn * 1024 + 16);

        if ((fbits >> (w * 16 + kt)) & 1ull) {   // nonzero mask tile: rare path
            const float* mr = mask + (size_t)b * SEQ * SEQ
                            + (size_t)(qs0 + l31) * SEQ + k0 + kt * 32 + hi * 4;
            union { float4 f4[4]; float f[16]; } mu;
            mu.f4[0] = *(const float4*)(mr);
            mu.f4[1] = *(const float4*)(mr + 8);
            mu.f4[2] = *(const float4*)(mr + 16);
            mu.f4[3] = *(const float4*)(mr + 24);
            #pragma unroll
            for (int j = 0; j < 16; j++) st[j] = fmaf(mu.f[j], LOG2E, st[j]);
        }

        float x0 = fmaxf(st[0], st[1]),  x1 = fmaxf(st[2], st[3]);
        float x2 = fmaxf(st[4], st[5]),  x3 = fmaxf(st[6], st[7]);
        float x4 = fmaxf(st[8], st[9]),  x5 = fmaxf(st[10], st[11]);
        float x6 = fmaxf(st[12], st[13]), x7 = fmaxf(st[14], st[15]);
        float lmax = fmaxf(fmaxf(fmaxf(x0, x1), fmaxf(x2, x3)),
                           fmaxf(fmaxf(x4, x5), fmaxf(x6, x7)));

        if (__any(lmax > mrun + THRS)) {   // defer-max rescale (rare)
            v2i sw = __builtin_amdgcn_permlane32_swap(
                __float_as_int(lmax), __float_as_int(lmax), false, false);
            float pm = fmaxf(fmaxf(lmax, __int_as_float(sw.x)), __int_as_float(sw.y));
            float nm = fmaxf(mrun, pm);
            float sc = exp2a(mrun - nm);
            lsum *= sc;
            #pragma unroll
            for (int j = 0; j < 16; j++) acc[j] *= sc;   // q = own lane: no shuffle
            mrun = nm;
        }

        float ev[16];
        #pragma unroll
        for (int j = 0; j < 16; j++) ev[j] = exp2a(st[j] - mrun);
        lsum += (((ev[0]+ev[1])+(ev[2]+ev[3])) + ((ev[4]+ev[5])+(ev[6]+ev[7])))
              + (((ev[8]+ev[9])+(ev[10]+ev[11])) + ((ev[12]+ev[13])+(ev[14]+ev[15])));

        unsigned pk[8];
        #pragma unroll
        for (int j = 0; j < 8; j++) pk[j] = cvtpk(ev[2 * j], ev[2 * j + 1]);
        // P^T B-operand repack via permlane32_swap (HW-verified R7):
        v2i p0 = __builtin_amdgcn_permlane32_swap((int)pk[0], (int)pk[2], false, false);
        v2i p1 = __builtin_amdgcn_permlane32_swap((int)pk[1], (int)pk[3], false, false);
        v2i p2 = __builtin_amdgcn_permlane32_swap((int)pk[4], (int)pk[6], false, false);
        v2i p3 = __builtin_amdgcn_permlane32_swap((int)pk[5], (int)pk[7], false, false);
        union { int i[4]; bf16x8 v; } pf0, pf1;
        pf0.i[0] = p0.x; pf0.i[1] = p1.x; pf0.i[2] = p0.y; pf0.i[3] = p1.y;
        pf1.i[0] = p2.x; pf1.i[1] = p3.x; pf1.i[2] = p2.y; pf1.i[3] = p3.y;

        acc = __builtin_amdgcn_mfma_f32_32x32x16_bf16(vc0, pf0.v, acc, 0, 0, 0);
        acc = __builtin_amdgcn_mfma_f32_32x32x16_bf16(vc1, pf1.v, acc, 0, 0, 0);

        kc0 = kn0; kc1 = kn1; vc0 = vn0; vc1 = vn1;
    }

    // lsum across the two half-lanes of each q
    v2i sl = __builtin_amdgcn_permlane32_swap(
        __float_as_int(lsum), __float_as_int(lsum), false, false);
    float lt = __int_as_float(sl.x) + __int_as_float(sl.y);
    if (hi == 0) { om[w][l31] = mrun; ol[w][l31] = lt; }

    #pragma unroll
    for (int gg = 0; gg < 4; gg++) {    // acc reg 4g+j -> d = j + 8g + 4hi
        f32x4 vv = { acc[4*gg], acc[4*gg+1], acc[4*gg+2], acc[4*gg+3] };
        *(f32x4*)&oacc[w][l31][8 * gg + 4 * hi] = vv;
    }
    __syncthreads();

    // merge 4 k-quarters: 1024 outputs, one float4 per thread
    int t = threadIdx.x;
    int q = t >> 3, d4 = (t & 7) * 4;
    float m0 = om[0][q], m1 = om[1][q], m2 = om[2][q], m3 = om[3][q];
    float mg = fmaxf(fmaxf(m0, m1), fmaxf(m2, m3));
    float w0_ = exp2a(m0 - mg), w1_ = exp2a(m1 - mg);
    float w2_ = exp2a(m2 - mg), w3_ = exp2a(m3 - mg);
    float lg = w0_ * ol[0][q] + w1_ * ol[1][q] + w2_ * ol[2][q] + w3_ * ol[3][q];
    float inv = 1.0f / lg;
    float4 o;
    o.x = (w0_*oacc[0][q][d4]   + w1_*oacc[1][q][d4]   + w2_*oacc[2][q][d4]   + w3_*oacc[3][q][d4])   * inv;
    o.y = (w0_*oacc[0][q][d4+1] + w1_*oacc[1][q][d4+1] + w2_*oacc[2][q][d4+1] + w3_*oacc[3][q][d4+1]) * inv;
    o.z = (w0_*oacc[0][q][d4+2] + w1_*oacc[1][q][d4+2] + w2_*oacc[2][q][d4+2] + w3_*oacc[3][q][d4+2]) * inv;
    o.w = (w0_*oacc[0][q][d4+3] + w1_*oacc[1][q][d4+3] + w2_*oacc[2][q][d4+3] + w3_*oacc[3][q][d4+3]) * inv;
    *(float4*)(out + ((size_t)(qs0 + q) * BATCH + b) * EMS + h * HEAD + d4) = o;
}

extern "C" void kernel_launch(void* const* d_in, const int* in_sizes, int n_in,
                              void* d_out, int out_size, void* d_ws, size_t ws_size,
                              hipStream_t stream) {
    const float* em  = (const float*)d_in[0];
    const float* mask = (const float*)d_in[1];
    const float* Wq  = (const float*)d_in[2];
    const float* bq  = (const float*)d_in[3];
    const float* Wk  = (const float*)d_in[4];
    const float* bk  = (const float*)d_in[5];
    const float* Wv  = (const float*)d_in[6];
    const float* bv  = (const float*)d_in[7];
    float* out = (float*)d_out;

    ushort_t* Qb  = (ushort_t*)d_ws;                      // [BH][S][D] bf16, 2MB
    ushort_t* Kb  = Qb + (size_t)BH * SEQ * HEAD;         // 2MB
    ushort_t* Vt2 = Kb + (size_t)BH * SEQ * HEAD;         // [BH][64][32d][32s] bf16, 2MB
    unsigned* flagsU = (unsigned*)(Vt2 + (size_t)BH * SEQ * HEAD);  // 2KB

    fused_pre<<<dim3(896), dim3(256), 0, stream>>>(em, mask, Wq, bq, Wk, bk, Wv, bv,
                                                   Qb, Kb, Vt2, flagsU);
    attn<<<dim3(1024), dim3(256), 0, stream>>>(Qb, Kb, Vt2, mask,
                                               (const unsigned long long*)flagsU, out);
}